// Round 2
// baseline (771.287 us; speedup 1.0000x reference)
//
#include <hip/hip_runtime.h>

#define DEV __device__ __forceinline__

typedef __attribute__((ext_vector_type(8))) short short8;
typedef __attribute__((ext_vector_type(4))) float f32x4;

DEV float fast_rcp(float x) { return __builtin_amdgcn_rcpf(x); }
DEV float sigm(float x) { return fast_rcp(1.0f + __expf(-x)); }
DEV float tanhf_fast(float x) { return 1.0f - 2.0f * fast_rcp(1.0f + __expf(2.0f * x)); }

DEV short f2bf(float f) {
    unsigned u = __float_as_uint(f);
    unsigned r = (u + 0x7FFFu + ((u >> 16) & 1u)) >> 16;
    return (short)r;
}
DEV float bf2f(short h) {
    return __uint_as_float(((unsigned)(unsigned short)h) << 16);
}
DEV void split1(float f, short& h, short& l) {
    h = f2bf(f);
    l = f2bf(f - bf2f(h));
}
DEV void split8(const float4& x0, const float4& x1, short8& h, short8& l) {
    float fv[8] = {x0.x, x0.y, x0.z, x0.w, x1.x, x1.y, x1.z, x1.w};
#pragma unroll
    for (int j = 0; j < 8; ++j) { short hh, ll; split1(fv[j], hh, ll); h[j] = hh; l[j] = ll; }
}
#define MFMA16 __builtin_amdgcn_mfma_f32_16x16x32_bf16
DEV f32x4 mfma3(const short8& ah, const short8& al, const short8& bh, const short8& bl, f32x4 acc) {
    acc = MFMA16(ah, bh, acc, 0, 0, 0);
    acc = MFMA16(al, bh, acc, 0, 0, 0);
    acc = MFMA16(ah, bl, acc, 0, 0, 0);
    return acc;
}

// ---------------------------------------------------------------------------
// One-shot weight conversion: fp32 -> bf16 hi + bf16 lo (same flat layout).
// ---------------------------------------------------------------------------
__global__ __launch_bounds__(256) void convert_w_kernel(
    const float* __restrict__ p0, const float* __restrict__ p1,
    const float* __restrict__ p2, const float* __restrict__ p3,
    const float* __restrict__ p4, const float* __restrict__ p5,
    const float* __restrict__ p6, const float* __restrict__ p7,
    const float* __restrict__ p8, const float* __restrict__ p9,
    const float* __restrict__ p10, const float* __restrict__ p11,
    short* __restrict__ hi, short* __restrict__ lo)
{
    // cumulative boundaries in float4 units
    const int c1 = 8192, c2 = 16384, c3 = 90112, c4 = 139264, c5 = 155648,
              c6 = 221184, c7 = 483328, c8 = 745472, c9 = 1007616,
              c10 = 1269760, c11 = 2908160, total = 4546560;
    for (int v = blockIdx.x * 256 + threadIdx.x; v < total; v += gridDim.x * 256) {
        const float* s = p0; int base = 0;
        if (v >= c1)  { s = p1;  base = c1; }
        if (v >= c2)  { s = p2;  base = c2; }
        if (v >= c3)  { s = p3;  base = c3; }
        if (v >= c4)  { s = p4;  base = c4; }
        if (v >= c5)  { s = p5;  base = c5; }
        if (v >= c6)  { s = p6;  base = c6; }
        if (v >= c7)  { s = p7;  base = c7; }
        if (v >= c8)  { s = p8;  base = c8; }
        if (v >= c9)  { s = p9;  base = c9; }
        if (v >= c10) { s = p10; base = c10; }
        if (v >= c11) { s = p11; base = c11; }
        float4 f = ((const float4*)s)[v - base];
        short4 h, l;
        split1(f.x, h.x, l.x);
        split1(f.y, h.y, l.y);
        split1(f.z, h.z, l.z);
        split1(f.w, h.w, l.w);
        ((short4*)hi)[v] = h;
        ((short4*)lo)[v] = l;
    }
}

// ---------------------------------------------------------------------------
// Fused FC: out = act(A @ W^T + b).  Full-K, no partials.
// Two independent K-segments assigned to wave-groups kk=0/1, LDS-reduced.
// Block 512 thr = 8 waves = kk(2) x mtile(4 of 16 rows).  Block covers
// 64 rows x 16 cols; grid = (N/16, M/64).  All K multiples of 32.
// ---------------------------------------------------------------------------
__global__ __launch_bounds__(512) void fc_fused_kernel(
    const float* __restrict__ A1, int lda1,
    const short* __restrict__ W1hi, const short* __restrict__ W1lo, int ldw1, int K1,
    const float* __restrict__ A2, int lda2,
    const short* __restrict__ W2hi, const short* __restrict__ W2lo, int ldw2, int K2,
    const float* __restrict__ bias, float* __restrict__ out, int N, int act)
{
    __shared__ float red[4][64][17];
    const int tid = threadIdx.x, w = tid >> 6, kk = w >> 2, mtw = w & 3;
    const int lane = tid & 63, q = lane >> 4, r = lane & 15;
    const int rowbase = blockIdx.y * 64 + mtw * 16, n0 = blockIdx.x * 16;

    const float* A = kk ? A2 : A1;
    const int lda = kk ? lda2 : lda1, K = kk ? K2 : K1, ldw = kk ? ldw2 : ldw1;
    const short* Whi = kk ? W2hi : W1hi;
    const short* Wlo = kk ? W2lo : W1lo;
    const float* ar = A + (size_t)(rowbase + r) * lda;
    const short* wh = Whi + (size_t)(n0 + r) * ldw;
    const short* wl = Wlo + (size_t)(n0 + r) * ldw;

    f32x4 acc = {0.f, 0.f, 0.f, 0.f};
    float4 a0A, a1A, a0B, a1B;
    short8 bhA, blA, bhB, blB;

    auto ld = [&](int k0, float4& x0, float4& x1, short8& bh, short8& bl) {
        x0 = *(const float4*)(ar + k0 + q * 8);
        x1 = *(const float4*)(ar + k0 + q * 8 + 4);
        bh = *(const short8*)(wh + k0 + q * 8);
        bl = *(const short8*)(wl + k0 + q * 8);
    };
    auto cp = [&](const float4& x0, const float4& x1, const short8& bh, const short8& bl) {
        short8 ah, al;
        split8(x0, x1, ah, al);
        acc = mfma3(ah, al, bh, bl, acc);
    };

    const int ns = K >> 5;
    ld(0, a0A, a1A, bhA, blA);
    for (int s = 0; s + 1 < ns; ++s) {
        if (s & 1) { ld((s + 1) << 5, a0A, a1A, bhA, blA); cp(a0B, a1B, bhB, blB); }
        else       { ld((s + 1) << 5, a0B, a1B, bhB, blB); cp(a0A, a1A, bhA, blA); }
    }
    if ((ns - 1) & 1) cp(a0B, a1B, bhB, blB);
    else              cp(a0A, a1A, bhA, blA);

    if (kk) {
#pragma unroll
        for (int i = 0; i < 4; ++i) red[mtw][lane][i] = acc[i];
    }
    __syncthreads();
    if (!kk) {
        float b = bias ? bias[n0 + r] : 0.f;
#pragma unroll
        for (int i = 0; i < 4; ++i) {
            float v = acc[i] + red[mtw][lane][i] + b;
            if (act) v = tanhf_fast(v);
            out[(size_t)(rowbase + q * 4 + i) * N + n0 + r] = v;
        }
    }
}

// ---------------------------------------------------------------------------
// Fused GRU cell.  kk=0 computes gi = [ctx|pout] @ wih^T (K=256+128),
// kk=1 computes gh = h_old @ whh^T (K=256); LDS exchange; full gate math.
// Gates [r,z,n] at W rows g*256+d.  Grid (256/16, 2), 512 thr.
// ---------------------------------------------------------------------------
__global__ __launch_bounds__(512) void gru_fused_kernel(
    const float* __restrict__ ctx, const float* __restrict__ pout,
    const short* __restrict__ Wihi, const short* __restrict__ Wilo,
    const short* __restrict__ Whhi, const short* __restrict__ Whlo,
    const float* __restrict__ bih, const float* __restrict__ bhh,
    const float* __restrict__ h_old, float* __restrict__ h_new)
{
    __shared__ float red[4][64][13];
    const int tid = threadIdx.x, w = tid >> 6, kk = w >> 2, mtw = w & 3;
    const int lane = tid & 63, q = lane >> 4, r = lane & 15;
    const int rowbase = blockIdx.y * 64 + mtw * 16, d0 = blockIdx.x * 16, col = d0 + r;

    const float* A1 = kk ? h_old : ctx;
    const int K1 = 256, Ktot = kk ? 256 : 384, ldw = kk ? 256 : 384;
    const short* Whi = kk ? Whhi : Wihi;
    const short* Wlo = kk ? Whlo : Wilo;

    const short* wh[3]; const short* wl[3];
#pragma unroll
    for (int g = 0; g < 3; ++g) {
        size_t ro = (size_t)(g * 256 + col) * ldw;
        wh[g] = Whi + ro; wl[g] = Wlo + ro;
    }
    const float* ar1 = A1 + (size_t)(rowbase + r) * 256;
    const float* ar2 = pout + (size_t)(rowbase + r) * 128;

    f32x4 acc[3] = {{0,0,0,0},{0,0,0,0},{0,0,0,0}};
    float4 a0A, a1A, a0B, a1B;
    short8 bhA[3], blA[3], bhB[3], blB[3];

    auto ld = [&](int kv, float4& x0, float4& x1, short8 (&bh)[3], short8 (&bl)[3]) {
        const float* ap = (kv < K1) ? (ar1 + kv) : (ar2 + kv - K1);
        x0 = *(const float4*)(ap + q * 8);
        x1 = *(const float4*)(ap + q * 8 + 4);
#pragma unroll
        for (int g = 0; g < 3; ++g) {
            bh[g] = *(const short8*)(wh[g] + kv + q * 8);
            bl[g] = *(const short8*)(wl[g] + kv + q * 8);
        }
    };
    auto cp = [&](const float4& x0, const float4& x1, const short8 (&bh)[3], const short8 (&bl)[3]) {
        short8 ah, al;
        split8(x0, x1, ah, al);
#pragma unroll
        for (int g = 0; g < 3; ++g) acc[g] = mfma3(ah, al, bh[g], bl[g], acc[g]);
    };

    const int ns = Ktot >> 5;
    ld(0, a0A, a1A, bhA, blA);
    for (int s = 0; s + 1 < ns; ++s) {
        if (s & 1) { ld((s + 1) << 5, a0A, a1A, bhA, blA); cp(a0B, a1B, bhB, blB); }
        else       { ld((s + 1) << 5, a0B, a1B, bhB, blB); cp(a0A, a1A, bhA, blA); }
    }
    if ((ns - 1) & 1) cp(a0B, a1B, bhB, blB);
    else              cp(a0A, a1A, bhA, blA);

    if (kk) {
#pragma unroll
        for (int g = 0; g < 3; ++g)
#pragma unroll
            for (int i = 0; i < 4; ++i) red[mtw][lane][g * 4 + i] = acc[g][i];
    }
    __syncthreads();
    if (!kk) {
#pragma unroll
        for (int i = 0; i < 4; ++i) {
            int row = rowbase + q * 4 + i;
            float ir = acc[0][i] + bih[col],       hr = red[mtw][lane][0 + i] + bhh[col];
            float iz = acc[1][i] + bih[256 + col], hz = red[mtw][lane][4 + i] + bhh[256 + col];
            float in = acc[2][i] + bih[512 + col], hn = red[mtw][lane][8 + i] + bhh[512 + col];
            float rr = sigm(ir + hr), zz = sigm(iz + hz);
            float nn = tanhf_fast(in + rr * hn);
            float ho = h_old[(size_t)row * 256 + col];
            h_new[(size_t)row * 256 + col] = (1.f - zz) * nn + zz * ho;
        }
    }
}

// ---------------------------------------------------------------------------
// Fused LSTM cell (also used for residual stack).  kk=0: x-side GEMM (wih),
// kk=1: h-side GEMM (whh); LDS exchange; gates [i,f,g,o] at W rows g*H+d;
// epilogue does cell update + x_new = x_old + h2 (+ optional cond copy).
// Grid (H/16, 2), 512 thr.
// ---------------------------------------------------------------------------
__global__ __launch_bounds__(512) void lstm_fused_kernel(
    const float* __restrict__ Ax, const short* __restrict__ Wxhi, const short* __restrict__ Wxlo,
    const float* __restrict__ Ah, const short* __restrict__ Whhi, const short* __restrict__ Whlo,
    int K, int H,
    const float* __restrict__ bih, const float* __restrict__ bhh,
    const float* __restrict__ c_in, float* __restrict__ h_out, float* __restrict__ c_out,
    const float* __restrict__ x_old, float* __restrict__ x_new, float* __restrict__ cond)
{
    __shared__ float red[4][64][17];
    const int tid = threadIdx.x, w = tid >> 6, kk = w >> 2, mtw = w & 3;
    const int lane = tid & 63, q = lane >> 4, r = lane & 15;
    const int rowbase = blockIdx.y * 64 + mtw * 16, d0 = blockIdx.x * 16, col = d0 + r;

    const float* A = kk ? Ah : Ax;
    const short* Whi = kk ? Whhi : Wxhi;
    const short* Wlo = kk ? Whlo : Wxlo;

    const short* wh[4]; const short* wl[4];
#pragma unroll
    for (int g = 0; g < 4; ++g) {
        size_t ro = (size_t)(g * H + col) * K;
        wh[g] = Whi + ro; wl[g] = Wlo + ro;
    }
    const float* ar = A + (size_t)(rowbase + r) * K;

    f32x4 acc[4] = {{0,0,0,0},{0,0,0,0},{0,0,0,0},{0,0,0,0}};
    float4 a0A, a1A, a0B, a1B;
    short8 bhA[4], blA[4], bhB[4], blB[4];

    auto ld = [&](int k0, float4& x0, float4& x1, short8 (&bh)[4], short8 (&bl)[4]) {
        x0 = *(const float4*)(ar + k0 + q * 8);
        x1 = *(const float4*)(ar + k0 + q * 8 + 4);
#pragma unroll
        for (int g = 0; g < 4; ++g) {
            bh[g] = *(const short8*)(wh[g] + k0 + q * 8);
            bl[g] = *(const short8*)(wl[g] + k0 + q * 8);
        }
    };
    auto cp = [&](const float4& x0, const float4& x1, const short8 (&bh)[4], const short8 (&bl)[4]) {
        short8 ah, al;
        split8(x0, x1, ah, al);
#pragma unroll
        for (int g = 0; g < 4; ++g) acc[g] = mfma3(ah, al, bh[g], bl[g], acc[g]);
    };

    const int ns = K >> 5;
    ld(0, a0A, a1A, bhA, blA);
    for (int s = 0; s + 1 < ns; ++s) {
        if (s & 1) { ld((s + 1) << 5, a0A, a1A, bhA, blA); cp(a0B, a1B, bhB, blB); }
        else       { ld((s + 1) << 5, a0B, a1B, bhB, blB); cp(a0A, a1A, bhA, blA); }
    }
    if ((ns - 1) & 1) cp(a0B, a1B, bhB, blB);
    else              cp(a0A, a1A, bhA, blA);

    if (kk) {
#pragma unroll
        for (int g = 0; g < 4; ++g)
#pragma unroll
            for (int i = 0; i < 4; ++i) red[mtw][lane][g * 4 + i] = acc[g][i];
    }
    __syncthreads();
    if (!kk) {
#pragma unroll
        for (int i = 0; i < 4; ++i) {
            int row = rowbase + q * 4 + i;
            float iv = acc[0][i] + red[mtw][lane][0 + i]  + bih[col] + bhh[col];
            float fv = acc[1][i] + red[mtw][lane][4 + i]  + bih[H + col] + bhh[H + col];
            float gv = acc[2][i] + red[mtw][lane][8 + i]  + bih[2 * H + col] + bhh[2 * H + col];
            float ov = acc[3][i] + red[mtw][lane][12 + i] + bih[3 * H + col] + bhh[3 * H + col];
            size_t o = (size_t)row * H + col;
            float c2 = sigm(fv) * c_in[o] + sigm(iv) * tanhf_fast(gv);
            float h2 = sigm(ov) * tanhf_fast(c2);
            h_out[o] = h2;
            c_out[o] = c2;
            float xn = x_old[o] + h2;
            x_new[o] = xn;
            if (cond) cond[o] = xn;
        }
    }
}

// ---------------------------------------------------------------------------
// L_w -> bf16 (row-major [d=256][c=32]).  8192 elems.
// ---------------------------------------------------------------------------
__global__ void lw_bf16_kernel(const float* __restrict__ Lw, short* __restrict__ LwBf)
{
    int i = blockIdx.x * 256 + threadIdx.x;
    LwBf[i] = f2bf(Lw[i]);
}

// ---------------------------------------------------------------------------
// Fused LSA u-kernel (unchanged, harness-verified).
// ---------------------------------------------------------------------------
__global__ __launch_bounds__(256) void attn_u_kernel(
    const float* __restrict__ esp, const float* __restrict__ pq,
    const short* __restrict__ LwBf, const float* __restrict__ Lb,
    const float* __restrict__ vw, const float* __restrict__ cw,
    const float* __restrict__ cum, const float* __restrict__ prev,
    float* __restrict__ sig_out)
{
    const int b = blockIdx.x >> 4;
    const int t0 = (blockIdx.x & 15) << 6;
    const int tid = threadIdx.x;

    __shared__ float cum_s[94], prev_s[94];
    __shared__ float cw_s[2][32][33];
    __shared__ short conv_bf[64 * 32];
    __shared__ short lw_bf[256 * 32];
    __shared__ float pq_s[256], vw_s[256];

    if (tid < 94) {
        int ti = t0 - 15 + tid;
        cum_s[tid] = (ti >= 0 && ti < 1024) ? cum[b * 1024 + ti] : 0.f;
    } else if (tid >= 128 && tid < 222) {
        int i = tid - 128;
        int ti = t0 - 15 + i;
        prev_s[i] = (ti >= 0 && ti < 1024) ? prev[b * 1024 + ti] : 0.f;
    }
    for (int i = tid; i < 2048; i += 256) {
        int which = i >> 10, c = (i >> 5) & 31, k = i & 31;
        cw_s[which][c][k] = (k < 31) ? cw[(c * 2 + which) * 31 + k] : 0.f;
    }
    {
        const int4* src = (const int4*)LwBf;
        int4* dst = (int4*)lw_bf;
#pragma unroll
        for (int k = 0; k < 4; ++k) dst[tid + k * 256] = src[tid + k * 256];
    }
    pq_s[tid] = pq[b * 256 + tid] + Lb[tid];
    vw_s[tid] = vw[tid];
    __syncthreads();

    {
        int c = tid & 31, t8 = (tid >> 5) << 3;
        float a[8] = {0.f, 0.f, 0.f, 0.f, 0.f, 0.f, 0.f, 0.f};
        for (int k = 0; k < 31; ++k) {
            float w0 = cw_s[0][c][k], w1 = cw_s[1][c][k];
#pragma unroll
            for (int j = 0; j < 8; ++j)
                a[j] += w0 * cum_s[t8 + j + k] + w1 * prev_s[t8 + j + k];
        }
#pragma unroll
        for (int j = 0; j < 8; ++j) conv_bf[(t8 + j) * 32 + c] = f2bf(a[j]);
    }
    __syncthreads();

    const int lane = tid & 63, w = tid >> 6;
    const int q = lane >> 4, c16 = lane & 15;
    const int myt = t0 + w * 16 + c16;

    short8 bfrag = *(const short8*)&conv_bf[(w * 16 + c16) * 32 + q * 8];
    const float* er = esp + ((size_t)(b * 1024 + myt) << 8);

    float s = 0.f;
#pragma unroll
    for (int dt = 0; dt < 16; ++dt) {
        short8 afrag = *(const short8*)&lw_bf[(dt * 16 + c16) * 32 + q * 8];
        f32x4 acc = {0.f, 0.f, 0.f, 0.f};
        acc = MFMA16(afrag, bfrag, acc, 0, 0, 0);
        const int d0 = dt * 16 + q * 4;
        float4 e   = *(const float4*)(er + d0);
        float4 pqv = *(const float4*)&pq_s[d0];
        float4 vwv = *(const float4*)&vw_s[d0];
        s += tanhf_fast(pqv.x + e.x + acc[0]) * vwv.x;
        s += tanhf_fast(pqv.y + e.y + acc[1]) * vwv.y;
        s += tanhf_fast(pqv.z + e.z + acc[2]) * vwv.z;
        s += tanhf_fast(pqv.w + e.w + acc[3]) * vwv.w;
    }
    s += __shfl_xor(s, 16);
    s += __shfl_xor(s, 32);
    if (lane < 16)
        sig_out[b * 1024 + t0 + w * 16 + lane] = sigm(s);
}

// ---------------------------------------------------------------------------
__global__ void attn_norm_kernel(const float* __restrict__ sig, const float* __restrict__ cum,
                                 float* __restrict__ scores, float* __restrict__ cum_new,
                                 float* __restrict__ ctx)
{
    __shared__ float red[4];
    int b = blockIdx.x, tid = threadIdx.x;
    float4 sv = *(const float4*)&sig[b * 1024 + tid * 4];
    float s = sv.x + sv.y + sv.z + sv.w;
#pragma unroll
    for (int off = 1; off < 64; off <<= 1) s += __shfl_xor(s, off);
    if ((tid & 63) == 0) red[tid >> 6] = s;
    __syncthreads();
    float inv = fast_rcp(red[0] + red[1] + red[2] + red[3]);
    float4 cv = *(const float4*)&cum[b * 1024 + tid * 4];
    float4 sc = {sv.x * inv, sv.y * inv, sv.z * inv, sv.w * inv};
    *(float4*)&scores[b * 1024 + tid * 4] = sc;
    float4 cn = {cv.x + sc.x, cv.y + sc.y, cv.z + sc.z, cv.w + sc.w};
    *(float4*)&cum_new[b * 1024 + tid * 4] = cn;
    ctx[b * 256 + tid] = 0.f;
}

// ---------------------------------------------------------------------------
__global__ void attn_ctx_kernel(const float* __restrict__ scores, const float* __restrict__ es,
                                float* __restrict__ ctx)
{
    __shared__ float sc_s[128];
    int b = blockIdx.x >> 3;
    int tbase = (blockIdx.x & 7) * 128;
    int tid = threadIdx.x;
    if (tid < 128) sc_s[tid] = scores[b * 1024 + tbase + tid];
    __syncthreads();
    float a = 0.f;
    const float* ep = es + ((size_t)(b * 1024 + tbase)) * 256 + tid;
#pragma unroll 4
    for (int tt = 0; tt < 128; ++tt)
        a += sc_s[tt] * ep[(size_t)tt * 256];
    atomicAdd(&ctx[b * 256 + tid], a);
}

// ---------------------------------------------------------------------------
__global__ void build_rescat_kernel(const float* __restrict__ pre, const float* __restrict__ x,
                                    float* __restrict__ res)
{
    int idx = blockIdx.x * 256 + threadIdx.x;
    int m = idx / 640, d = idx - m * 640;
    res[idx] = (d < 128) ? pre[m * 128 + d] : x[m * 512 + d - 128];
}

__global__ void stop_kernel(const float* __restrict__ res, const float* __restrict__ sw,
                            const float* __restrict__ sb, float* __restrict__ stop)
{
    int m = blockIdx.x, lane = threadIdx.x;
    float s = 0.f;
    for (int k = lane; k < 640; k += 64) s += res[m * 640 + k] * sw[k];
#pragma unroll
    for (int off = 1; off < 64; off <<= 1) s += __shfl_xor(s, off);
    if (lane == 0) stop[m] = sigm(s + sb[0]);
}

// ---------------------------------------------------------------------------
extern "C" void kernel_launch(void* const* d_in, const int* in_sizes, int n_in,
                              void* d_out, int out_size, void* d_ws, size_t ws_size,
                              hipStream_t stream)
{
    const float* encoder_seq      = (const float*)d_in[0];
    const float* encoder_seq_proj = (const float*)d_in[1];
    const float* prenet_in        = (const float*)d_in[2];
    const float* attn_hidden      = (const float*)d_in[3];
    const float* rnn1_h  = (const float*)d_in[4];
    const float* rnn1_c  = (const float*)d_in[5];
    const float* rnn2_h  = (const float*)d_in[6];
    const float* rnn2_c  = (const float*)d_in[7];
    const float* res_h   = (const float*)d_in[8];
    const float* res_c   = (const float*)d_in[9];
    const float* context_vec = (const float*)d_in[10];
    const float* cumulative  = (const float*)d_in[11];
    const float* attn_prev   = (const float*)d_in[12];
    const float* fc1_w = (const float*)d_in[13];
    const float* fc1_b = (const float*)d_in[14];
    const float* fc2_w = (const float*)d_in[15];
    const float* fc2_b = (const float*)d_in[16];
    const float* gru_wih = (const float*)d_in[17];
    const float* gru_whh = (const float*)d_in[18];
    const float* gru_bih = (const float*)d_in[19];
    const float* gru_bhh = (const float*)d_in[20];
    const float* conv_w = (const float*)d_in[21];
    const float* L_w = (const float*)d_in[22];
    const float* L_b = (const float*)d_in[23];
    const float* W_w = (const float*)d_in[24];
    const float* W_b = (const float*)d_in[25];
    const float* v_w = (const float*)d_in[26];
    const float* ri_w = (const float*)d_in[27];
    const float* ri_b = (const float*)d_in[28];
    const float* r1_wih = (const float*)d_in[29];
    const float* r1_whh = (const float*)d_in[30];
    const float* r1_bih = (const float*)d_in[31];
    const float* r1_bhh = (const float*)d_in[32];
    const float* r2_wih = (const float*)d_in[33];
    const float* r2_whh = (const float*)d_in[34];
    const float* r2_bih = (const float*)d_in[35];
    const float* r2_bhh = (const float*)d_in[36];
    const float* res_wih = (const float*)d_in[37];
    const float* res_whh = (const float*)d_in[38];
    const float* res_bih = (const float*)d_in[39];
    const float* res_bhh = (const float*)d_in[40];
    const float* stop_w = (const float*)d_in[41];
    const float* stop_b = (const float*)d_in[42];

    float* ws  = (float*)d_ws;
    float* out = (float*)d_out;

    // workspace offsets (floats)
    const size_t OFF_P    = 0;        // fc1 out [128,256]
    const size_t OFF_POUT = 32768;    // fc2 out [128,128]
    const size_t OFF_PQ   = 49152;    // [128,256]
    const size_t OFF_SIG  = 81920;    // [128,1024]
    const size_t OFF_X    = 212992;   // ri out [128,512]
    const size_t OFF_XB   = 278528;   // x + h1 [128,512]
    const size_t OFF_XC   = 344064;   // x + h1 + h2 [128,512]
    const size_t OFF_R0   = 409600;   // res ping [128,640]
    const size_t OFF_R1   = 491520;   // res pong [128,640]
    const size_t OFF_LWT  = 573440;   // bf16 L_w (16 KB)
    const size_t OFF_WBF  = 577536;   // bf16 split weights (hi then lo)

    // converted-weight element offsets (order matches convert_w_kernel)
    const size_t WOFF_FC1 = 0,        WOFF_FC2 = 32768,   WOFF_GI = 65536,
                 WOFF_GH  = 360448,   WOFF_WW  = 557056,  WOFF_RI = 622592,
                 WOFF_R1I = 884736,   WOFF_R1H = 1933312, WOFF_R2I = 2981888,
                 WOFF_R2H = 4030464,  WOFF_RESI = 5079040, WOFF_RESH = 11632640,
                 W_TOTAL  = 18186240;
    short* WHI = (short*)(ws + OFF_WBF);
    short* WLO = WHI + W_TOTAL;

    // output offsets (floats)
    const size_t O_COND   = 0;
    const size_t O_STOP   = 81920;
    const size_t O_SCORES = 82048;
    const size_t O_ATTNH  = 213120;
    const size_t O_H1     = 245888;
    const size_t O_C1     = 311424;
    const size_t O_H2     = 376960;
    const size_t O_C2     = 442496;
    const size_t O_HS     = 508032;
    const size_t O_CS     = 835712;
    const size_t O_CTX    = 1163392;
    const size_t O_CUM    = 1196160;

    // ---- weight conversion ----
    convert_w_kernel<<<2048, 256, 0, stream>>>(
        fc1_w, fc2_w, gru_wih, gru_whh, W_w, ri_w,
        r1_wih, r1_whh, r2_wih, r2_whh, res_wih, res_whh, WHI, WLO);

    short* lwbf = (short*)(ws + OFF_LWT);
    lw_bf16_kernel<<<32, 256, 0, stream>>>(L_w, lwbf);

    // PreNet fc1: N=256, K=128 (split 64|64)
    fc_fused_kernel<<<dim3(16, 2), 512, 0, stream>>>(
        prenet_in, 128, WHI + WOFF_FC1, WLO + WOFF_FC1, 128, 64,
        prenet_in + 64, 128, WHI + WOFF_FC1 + 64, WLO + WOFF_FC1 + 64, 128, 64,
        fc1_b, ws + OFF_P, 256, 1);
    // PreNet fc2: N=128, K=256 (split 128|128)
    fc_fused_kernel<<<dim3(8, 2), 512, 0, stream>>>(
        ws + OFF_P, 256, WHI + WOFF_FC2, WLO + WOFF_FC2, 256, 128,
        ws + OFF_P + 128, 256, WHI + WOFF_FC2 + 128, WLO + WOFF_FC2 + 128, 256, 128,
        fc2_b, ws + OFF_POUT, 128, 1);

    // GRU (fused): gi = [ctx|pout] @ wih^T, gh = h @ whh^T, gate math
    gru_fused_kernel<<<dim3(16, 2), 512, 0, stream>>>(
        context_vec, ws + OFF_POUT,
        WHI + WOFF_GI, WLO + WOFF_GI, WHI + WOFF_GH, WLO + WOFF_GH,
        gru_bih, gru_bhh, attn_hidden, out + O_ATTNH);

    // pq: N=256, K=256 (split 128|128)
    fc_fused_kernel<<<dim3(16, 2), 512, 0, stream>>>(
        out + O_ATTNH, 256, WHI + WOFF_WW, WLO + WOFF_WW, 256, 128,
        out + O_ATTNH + 128, 256, WHI + WOFF_WW + 128, WLO + WOFF_WW + 128, 256, 128,
        W_b, ws + OFF_PQ, 256, 0);

    attn_u_kernel<<<2048, 256, 0, stream>>>(encoder_seq_proj, ws + OFF_PQ, lwbf,
                                            L_b, v_w, conv_w, cumulative, attn_prev,
                                            ws + OFF_SIG);
    attn_norm_kernel<<<128, 256, 0, stream>>>(ws + OFF_SIG, cumulative,
                                              out + O_SCORES, out + O_CUM, out + O_CTX);
    attn_ctx_kernel<<<1024, 256, 0, stream>>>(out + O_SCORES, encoder_seq, out + O_CTX);

    // x = [context | attn_h] @ ri_w^T + ri_b : N=512, segments 256|256
    fc_fused_kernel<<<dim3(32, 2), 512, 0, stream>>>(
        out + O_CTX, 256, WHI + WOFF_RI, WLO + WOFF_RI, 512, 256,
        out + O_ATTNH, 256, WHI + WOFF_RI + 256, WLO + WOFF_RI + 256, 512, 256,
        ri_b, ws + OFF_X, 512, 0);

    // LSTM 1 (fused): x-side K=512, h-side K=512; XB = X + h1
    lstm_fused_kernel<<<dim3(32, 2), 512, 0, stream>>>(
        ws + OFF_X, WHI + WOFF_R1I, WLO + WOFF_R1I,
        rnn1_h, WHI + WOFF_R1H, WLO + WOFF_R1H,
        512, 512, r1_bih, r1_bhh, rnn1_c, out + O_H1, out + O_C1,
        ws + OFF_X, ws + OFF_XB, nullptr);
    // LSTM 2 (fused): XC = XB + h2
    lstm_fused_kernel<<<dim3(32, 2), 512, 0, stream>>>(
        ws + OFF_XB, WHI + WOFF_R2I, WLO + WOFF_R2I,
        rnn2_h, WHI + WOFF_R2H, WLO + WOFF_R2H,
        512, 512, r2_bih, r2_bhh, rnn2_c, out + O_H2, out + O_C2,
        ws + OFF_XB, ws + OFF_XC, nullptr);

    build_rescat_kernel<<<320, 256, 0, stream>>>(prenet_in, ws + OFF_XC, ws + OFF_R0);

    // Residual stack (fused), ping-pong R0/R1; layer 3 also writes cond out
    for (int i = 0; i < 4; ++i) {
        const float* rcur = ws + ((i & 1) ? OFF_R1 : OFF_R0);
        float* rnxt = ws + ((i & 1) ? OFF_R0 : OFF_R1);
        lstm_fused_kernel<<<dim3(40, 2), 512, 0, stream>>>(
            rcur, WHI + WOFF_RESI + (size_t)i * 2560 * 640, WLO + WOFF_RESI + (size_t)i * 2560 * 640,
            res_h + (size_t)i * 81920, WHI + WOFF_RESH + (size_t)i * 2560 * 640, WLO + WOFF_RESH + (size_t)i * 2560 * 640,
            640, 640,
            res_bih + (size_t)i * 2560, res_bhh + (size_t)i * 2560,
            res_c + (size_t)i * 81920,
            out + O_HS + (size_t)i * 81920, out + O_CS + (size_t)i * 81920,
            rcur, rnxt, (i == 3) ? (out + O_COND) : nullptr);
    }

    // final res buffer after layer 3 is R0
    stop_kernel<<<128, 64, 0, stream>>>(ws + OFF_R0, stop_w, stop_b, out + O_STOP);
}

// Round 4
// 632.764 us; speedup vs baseline: 1.2189x; 1.2189x over previous
//
#include <hip/hip_runtime.h>

#define DEV __device__ __forceinline__

typedef __attribute__((ext_vector_type(8))) short short8;
typedef __attribute__((ext_vector_type(4))) float f32x4;

DEV float fast_rcp(float x) { return __builtin_amdgcn_rcpf(x); }
DEV float sigm(float x) { return fast_rcp(1.0f + __expf(-x)); }
DEV float tanhf_fast(float x) { return 1.0f - 2.0f * fast_rcp(1.0f + __expf(2.0f * x)); }

DEV short f2bf(float f) {
    unsigned u = __float_as_uint(f);
    unsigned r = (u + 0x7FFFu + ((u >> 16) & 1u)) >> 16;
    return (short)r;
}
DEV float bf2f(short h) {
    return __uint_as_float(((unsigned)(unsigned short)h) << 16);
}
DEV void split1(float f, short& h, short& l) {
    h = f2bf(f);
    l = f2bf(f - bf2f(h));
}
DEV void split8(const float4& x0, const float4& x1, short8& h, short8& l) {
    float fv[8] = {x0.x, x0.y, x0.z, x0.w, x1.x, x1.y, x1.z, x1.w};
#pragma unroll
    for (int j = 0; j < 8; ++j) { short hh, ll; split1(fv[j], hh, ll); h[j] = hh; l[j] = ll; }
}
#define MFMA16 __builtin_amdgcn_mfma_f32_16x16x32_bf16
DEV f32x4 mfma3(const short8& ah, const short8& al, const short8& bh, const short8& bl, f32x4 acc) {
    acc = MFMA16(ah, bh, acc, 0, 0, 0);
    acc = MFMA16(al, bh, acc, 0, 0, 0);
    acc = MFMA16(ah, bl, acc, 0, 0, 0);
    return acc;
}

// ---------------------------------------------------------------------------
// Split-K 2-segment MFMA GEMM core.  A fp32 [128][K] row-major and W fp32
// [N][ldw] row-major are both split to bf16 hi/lo IN-REGISTER (fp32 = same
// HBM bytes as bf16 hi+lo, so no conversion pass / extra traffic).
// Out Cp[chunk][m=128][n]; 256 thr = 4 waves; wave w owns rows w*32..+31
// (2 m-tiles x 2 n-tiles of 16x16); 32-wide n-tile per block.
// Grid = (N/32)*KS; KC % 32 == 0; segment boundary K1 % 32 == 0.
// MFMA C/D layout (harness-verified): row = (lane>>4)*4+i, col = lane&15.
// ---------------------------------------------------------------------------
DEV void gemm_core(int bx,
                   const float* __restrict__ A1, int K1,
                   const float* __restrict__ W1, int ldw1,
                   const float* __restrict__ A2, int K2,
                   const float* __restrict__ W2, int ldw2,
                   float* __restrict__ Cp, int N, int KS, int KC)
{
    const int tid = threadIdx.x;
    const int chunk = bx % KS;
    const int n0 = (bx / KS) * 32;
    const int kbeg = chunk * KC;
    const int w = tid >> 6, lane = tid & 63;
    const int q = lane >> 4, r = lane & 15;
    const int m_base = w * 32;

    f32x4 acc[2][2];
#pragma unroll
    for (int mt = 0; mt < 2; ++mt)
#pragma unroll
        for (int nt = 0; nt < 2; ++nt)
            acc[mt][nt] = (f32x4){0.f, 0.f, 0.f, 0.f};

    auto load_frag = [&](int kg, float4 (&a)[2][2], float4 (&wv)[2][2]) {
        const float* A; const float* W; int lda, ldw, kc;
        if (kg < K1) { A = A1; W = W1; lda = K1; ldw = ldw1; kc = kg; }
        else         { A = A2; W = W2; lda = K2; ldw = ldw2; kc = kg - K1; }
#pragma unroll
        for (int mt = 0; mt < 2; ++mt) {
            const float* ap = A + (size_t)(m_base + mt * 16 + r) * lda + kc + q * 8;
            a[mt][0] = *(const float4*)ap;
            a[mt][1] = *(const float4*)(ap + 4);
        }
#pragma unroll
        for (int nt = 0; nt < 2; ++nt) {
            const float* wp = W + (size_t)(n0 + nt * 16 + r) * ldw + kc + q * 8;
            wv[nt][0] = *(const float4*)wp;
            wv[nt][1] = *(const float4*)(wp + 4);
        }
    };

    auto compute = [&](const float4 (&a)[2][2], const float4 (&wv)[2][2]) {
        short8 bh[2], bl[2];
#pragma unroll
        for (int nt = 0; nt < 2; ++nt) split8(wv[nt][0], wv[nt][1], bh[nt], bl[nt]);
#pragma unroll
        for (int mt = 0; mt < 2; ++mt) {
            short8 ah, al;
            split8(a[mt][0], a[mt][1], ah, al);
#pragma unroll
            for (int nt = 0; nt < 2; ++nt)
                acc[mt][nt] = mfma3(ah, al, bh[nt], bl[nt], acc[mt][nt]);
        }
    };

    float4 aA[2][2], aB[2][2], wA[2][2], wB[2][2];
    const int nsteps = KC >> 5;

    load_frag(kbeg, aA, wA);
    for (int s = 0; s + 1 < nsteps; ++s) {
        if (s & 1) { load_frag(kbeg + (s + 1) * 32, aA, wA); compute(aB, wB); }
        else       { load_frag(kbeg + (s + 1) * 32, aB, wB); compute(aA, wA); }
    }
    if ((nsteps - 1) & 1) compute(aB, wB);
    else                  compute(aA, wA);

    float* Co = Cp + (size_t)chunk * 128 * N;
#pragma unroll
    for (int mt = 0; mt < 2; ++mt)
#pragma unroll
        for (int nt = 0; nt < 2; ++nt)
#pragma unroll
            for (int i = 0; i < 4; ++i)
                Co[(size_t)(m_base + mt * 16 + q * 4 + i) * N + n0 + nt * 16 + r] = acc[mt][nt][i];
}

__global__ __launch_bounds__(256) void gemm_one_kernel(
    const float* __restrict__ A1, int K1, const float* __restrict__ W1, int ldw1,
    const float* __restrict__ A2, int K2, const float* __restrict__ W2, int ldw2,
    float* __restrict__ Cp, int N, int KS, int KC)
{
    gemm_core(blockIdx.x, A1, K1, W1, ldw1, A2, K2, W2, ldw2, Cp, N, KS, KC);
}

// GRU's two independent GEMMs (gi: 288 blocks, gh: 192 blocks) in one launch.
__global__ __launch_bounds__(256) void gemm_gru_kernel(
    const float* __restrict__ ctx, const float* __restrict__ pout,
    const float* __restrict__ h_old,
    const float* __restrict__ wih, const float* __restrict__ whh,
    float* __restrict__ Pa, float* __restrict__ Pb)
{
    if (blockIdx.x < 288)
        gemm_core(blockIdx.x, ctx, 256, wih, 384, pout, 128, wih + 256, 384,
                  Pa, 768, 12, 32);
    else
        gemm_core(blockIdx.x - 288, h_old, 256, whh, 256, nullptr, 0, nullptr, 0,
                  Pb, 768, 8, 32);
}

// ---------------------------------------------------------------------------
__global__ void reduce_act_kernel(const float* __restrict__ p, int KS, int MN,
                                  const float* __restrict__ b,
                                  float* __restrict__ out, int N, int act)
{
    int idx = blockIdx.x * 256 + threadIdx.x;
    if (idx >= MN) return;
    int n = idx % N;
    float v = b ? b[n] : 0.f;
    for (int s = 0; s < KS; ++s) v += p[(size_t)s * MN + idx];
    if (act) v = tanhf_fast(v);
    out[idx] = v;
}

// ---------------------------------------------------------------------------
__global__ void gru_gate_kernel(const float* __restrict__ gi_p, int KSi,
                                const float* __restrict__ gh_p, int KSh,
                                const float* __restrict__ bih, const float* __restrict__ bhh,
                                const float* __restrict__ h, float* __restrict__ out)
{
    const size_t MN = 128 * 768;
    int m = blockIdx.x, d = threadIdx.x;
    size_t base = (size_t)m * 768 + d;
    float ir = bih[d], iz = bih[256 + d], in = bih[512 + d];
    for (int s = 0; s < KSi; ++s) {
        const float* p = gi_p + s * MN + base;
        ir += p[0]; iz += p[256]; in += p[512];
    }
    float hr = bhh[d], hz = bhh[256 + d], hn = bhh[512 + d];
    for (int s = 0; s < KSh; ++s) {
        const float* p = gh_p + s * MN + base;
        hr += p[0]; hz += p[256]; hn += p[512];
    }
    float r = sigm(ir + hr);
    float z = sigm(iz + hz);
    float n = tanhf_fast(in + r * hn);
    out[m * 256 + d] = (1.f - z) * n + z * h[m * 256 + d];
}

// ---------------------------------------------------------------------------
// LSTM gate epilogue.  x_old is read through a 2-segment view
// (d < split ? xa[m*sa+d] : xb[m*sb+d-split]) so concats need no
// materialization (split=0 means pure xb).  x_new = x_old + h2.
// ---------------------------------------------------------------------------
__global__ void lstm_gate_kernel(const float* __restrict__ gp, int KS,
                                 const float* __restrict__ bih, const float* __restrict__ bhh,
                                 const float* __restrict__ c_in,
                                 float* __restrict__ h_out, float* __restrict__ c_out,
                                 const float* __restrict__ xa, int sa,
                                 const float* __restrict__ xb, int sb, int split,
                                 float* __restrict__ x_new, int H)
{
    int d = blockIdx.x * 256 + threadIdx.x;
    int m = blockIdx.y;
    if (d >= H) return;
    const size_t MN = (size_t)128 * 4 * H;
    size_t base = (size_t)m * 4 * H + d;
    float iv = bih[d] + bhh[d];
    float fv = bih[H + d] + bhh[H + d];
    float gv = bih[2 * H + d] + bhh[2 * H + d];
    float ov = bih[3 * H + d] + bhh[3 * H + d];
    for (int s = 0; s < KS; ++s) {
        const float* p = gp + s * MN + base;
        iv += p[0]; fv += p[H]; gv += p[2 * H]; ov += p[3 * H];
    }
    float c2 = sigm(fv) * c_in[(size_t)m * H + d] + sigm(iv) * tanhf_fast(gv);
    float h2 = sigm(ov) * tanhf_fast(c2);
    h_out[(size_t)m * H + d] = h2;
    c_out[(size_t)m * H + d] = c2;
    float xo = (d < split) ? xa[(size_t)m * sa + d] : xb[(size_t)m * sb + d - split];
    x_new[(size_t)m * H + d] = xo + h2;
}

// ---------------------------------------------------------------------------
// Fused LSA u-kernel: conv(loc) -> bf16 MFMA L-projection -> tanh -> v-dot ->
// sigmoid(u).  L_w read as fp32, converted to bf16 in the stage phase.
// grid(B*16) blocks (64 t's each), 256 threads (4 waves).
// ---------------------------------------------------------------------------
__global__ __launch_bounds__(256) void attn_u_kernel(
    const float* __restrict__ esp, const float* __restrict__ pq,
    const float* __restrict__ Lw, const float* __restrict__ Lb,
    const float* __restrict__ vw, const float* __restrict__ cw,
    const float* __restrict__ cum, const float* __restrict__ prev,
    float* __restrict__ sig_out)
{
    const int b = blockIdx.x >> 4;
    const int t0 = (blockIdx.x & 15) << 6;
    const int tid = threadIdx.x;

    __shared__ float cum_s[94], prev_s[94];
    __shared__ float cw_s[2][32][33];
    __shared__ short conv_bf[64 * 32];
    __shared__ short lw_bf[256 * 32];
    __shared__ float pq_s[256], vw_s[256];

    if (tid < 94) {
        int ti = t0 - 15 + tid;
        cum_s[tid] = (ti >= 0 && ti < 1024) ? cum[b * 1024 + ti] : 0.f;
    } else if (tid >= 128 && tid < 222) {
        int i = tid - 128;
        int ti = t0 - 15 + i;
        prev_s[i] = (ti >= 0 && ti < 1024) ? prev[b * 1024 + ti] : 0.f;
    }
    for (int i = tid; i < 2048; i += 256) {
        int which = i >> 10, c = (i >> 5) & 31, k = i & 31;
        cw_s[which][c][k] = (k < 31) ? cw[(c * 2 + which) * 31 + k] : 0.f;
    }
    {   // L_w fp32 -> bf16 into LDS (8192 elems, layout identical to source)
        const float4* src = (const float4*)Lw;
#pragma unroll
        for (int k = 0; k < 8; ++k) {
            float4 v = src[tid + k * 256];
            int base = (tid + k * 256) * 4;
            lw_bf[base + 0] = f2bf(v.x);
            lw_bf[base + 1] = f2bf(v.y);
            lw_bf[base + 2] = f2bf(v.z);
            lw_bf[base + 3] = f2bf(v.w);
        }
    }
    pq_s[tid] = pq[b * 256 + tid] + Lb[tid];
    vw_s[tid] = vw[tid];
    __syncthreads();

    {
        int c = tid & 31, t8 = (tid >> 5) << 3;
        float a[8] = {0.f, 0.f, 0.f, 0.f, 0.f, 0.f, 0.f, 0.f};
        for (int k = 0; k < 31; ++k) {
            float w0 = cw_s[0][c][k], w1 = cw_s[1][c][k];
#pragma unroll
            for (int j = 0; j < 8; ++j)
                a[j] += w0 * cum_s[t8 + j + k] + w1 * prev_s[t8 + j + k];
        }
#pragma unroll
        for (int j = 0; j < 8; ++j) conv_bf[(t8 + j) * 32 + c] = f2bf(a[j]);
    }
    __syncthreads();

    const int lane = tid & 63, w = tid >> 6;
    const int q = lane >> 4, c16 = lane & 15;
    const int myt = t0 + w * 16 + c16;

    short8 bfrag = *(const short8*)&conv_bf[(w * 16 + c16) * 32 + q * 8];
    const float* er = esp + ((size_t)(b * 1024 + myt) << 8);

    float s = 0.f;
#pragma unroll
    for (int dt = 0; dt < 16; ++dt) {
        short8 afrag = *(const short8*)&lw_bf[(dt * 16 + c16) * 32 + q * 8];
        f32x4 acc = {0.f, 0.f, 0.f, 0.f};
        acc = MFMA16(afrag, bfrag, acc, 0, 0, 0);
        const int d0 = dt * 16 + q * 4;
        float4 e   = *(const float4*)(er + d0);
        float4 pqv = *(const float4*)&pq_s[d0];
        float4 vwv = *(const float4*)&vw_s[d0];
        s += tanhf_fast(pqv.x + e.x + acc[0]) * vwv.x;
        s += tanhf_fast(pqv.y + e.y + acc[1]) * vwv.y;
        s += tanhf_fast(pqv.z + e.z + acc[2]) * vwv.z;
        s += tanhf_fast(pqv.w + e.w + acc[3]) * vwv.w;
    }
    s += __shfl_xor(s, 16);
    s += __shfl_xor(s, 32);
    if (lane < 16)
        sig_out[b * 1024 + t0 + w * 16 + lane] = sigm(s);
}

// ---------------------------------------------------------------------------
__global__ void attn_norm_kernel(const float* __restrict__ sig, const float* __restrict__ cum,
                                 float* __restrict__ scores, float* __restrict__ cum_new,
                                 float* __restrict__ ctx)
{
    __shared__ float red[4];
    int b = blockIdx.x, tid = threadIdx.x;
    float4 sv = *(const float4*)&sig[b * 1024 + tid * 4];
    float s = sv.x + sv.y + sv.z + sv.w;
#pragma unroll
    for (int off = 1; off < 64; off <<= 1) s += __shfl_xor(s, off);
    if ((tid & 63) == 0) red[tid >> 6] = s;
    __syncthreads();
    float inv = fast_rcp(red[0] + red[1] + red[2] + red[3]);
    float4 cv = *(const float4*)&cum[b * 1024 + tid * 4];
    float4 sc = {sv.x * inv, sv.y * inv, sv.z * inv, sv.w * inv};
    *(float4*)&scores[b * 1024 + tid * 4] = sc;
    float4 cn = {cv.x + sc.x, cv.y + sc.y, cv.z + sc.z, cv.w + sc.w};
    *(float4*)&cum_new[b * 1024 + tid * 4] = cn;
    ctx[b * 256 + tid] = 0.f;
}

// ---------------------------------------------------------------------------
__global__ void attn_ctx_kernel(const float* __restrict__ scores, const float* __restrict__ es,
                                float* __restrict__ ctx)
{
    __shared__ float sc_s[128];
    int b = blockIdx.x >> 3;
    int tbase = (blockIdx.x & 7) * 128;
    int tid = threadIdx.x;
    if (tid < 128) sc_s[tid] = scores[b * 1024 + tbase + tid];
    __syncthreads();
    float a = 0.f;
    const float* ep = es + ((size_t)(b * 1024 + tbase)) * 256 + tid;
#pragma unroll 4
    for (int tt = 0; tt < 128; ++tt)
        a += sc_s[tt] * ep[(size_t)tt * 256];
    atomicAdd(&ctx[b * 256 + tid], a);
}

// ---------------------------------------------------------------------------
__global__ void stop_kernel(const float* __restrict__ res, const float* __restrict__ sw,
                            const float* __restrict__ sb, float* __restrict__ stop)
{
    int m = blockIdx.x, lane = threadIdx.x;
    float s = 0.f;
    for (int k = lane; k < 640; k += 64) s += res[m * 640 + k] * sw[k];
#pragma unroll
    for (int off = 1; off < 64; off <<= 1) s += __shfl_xor(s, off);
    if (lane == 0) stop[m] = sigm(s + sb[0]);
}

// ---------------------------------------------------------------------------
extern "C" void kernel_launch(void* const* d_in, const int* in_sizes, int n_in,
                              void* d_out, int out_size, void* d_ws, size_t ws_size,
                              hipStream_t stream)
{
    const float* encoder_seq      = (const float*)d_in[0];
    const float* encoder_seq_proj = (const float*)d_in[1];
    const float* prenet_in        = (const float*)d_in[2];
    const float* attn_hidden      = (const float*)d_in[3];
    const float* rnn1_h  = (const float*)d_in[4];
    const float* rnn1_c  = (const float*)d_in[5];
    const float* rnn2_h  = (const float*)d_in[6];
    const float* rnn2_c  = (const float*)d_in[7];
    const float* res_h   = (const float*)d_in[8];
    const float* res_c   = (const float*)d_in[9];
    const float* context_vec = (const float*)d_in[10];
    const float* cumulative  = (const float*)d_in[11];
    const float* attn_prev   = (const float*)d_in[12];
    const float* fc1_w = (const float*)d_in[13];
    const float* fc1_b = (const float*)d_in[14];
    const float* fc2_w = (const float*)d_in[15];
    const float* fc2_b = (const float*)d_in[16];
    const float* gru_wih = (const float*)d_in[17];
    const float* gru_whh = (const float*)d_in[18];
    const float* gru_bih = (const float*)d_in[19];
    const float* gru_bhh = (const float*)d_in[20];
    const float* conv_w = (const float*)d_in[21];
    const float* L_w = (const float*)d_in[22];
    const float* L_b = (const float*)d_in[23];
    const float* W_w = (const float*)d_in[24];
    const float* W_b = (const float*)d_in[25];
    const float* v_w = (const float*)d_in[26];
    const float* ri_w = (const float*)d_in[27];
    const float* ri_b = (const float*)d_in[28];
    const float* r1_wih = (const float*)d_in[29];
    const float* r1_whh = (const float*)d_in[30];
    const float* r1_bih = (const float*)d_in[31];
    const float* r1_bhh = (const float*)d_in[32];
    const float* r2_wih = (const float*)d_in[33];
    const float* r2_whh = (const float*)d_in[34];
    const float* r2_bih = (const float*)d_in[35];
    const float* r2_bhh = (const float*)d_in[36];
    const float* res_wih = (const float*)d_in[37];
    const float* res_whh = (const float*)d_in[38];
    const float* res_bih = (const float*)d_in[39];
    const float* res_bhh = (const float*)d_in[40];
    const float* stop_w = (const float*)d_in[41];
    const float* stop_b = (const float*)d_in[42];

    float* ws  = (float*)d_ws;
    float* out = (float*)d_out;

    // workspace offsets (floats)
    const size_t OFF_P     = 0;        // fc1 out [128,256]
    const size_t OFF_POUT  = 32768;    // fc2 out [128,128]
    const size_t OFF_PQ    = 49152;    // [128,256]
    const size_t OFF_SIG   = 81920;    // [128,1024]
    const size_t OFF_X     = 212992;   // ri out [128,512]
    const size_t OFF_XB    = 278528;   // x + h1 [128,512]
    const size_t OFF_XC    = 344064;   // x + h1 + h2 [128,512]
    const size_t OFF_R0    = 409600;   // res ping [128,640]
    const size_t OFF_R1    = 491520;   // res pong [128,640]
    const size_t OFF_PART  = 573440;   // split-K partials A
    const size_t OFF_PARTB = OFF_PART + (size_t)12 * 128 * 768;    // GRU gh partials
    const size_t OFF_PARTH = OFF_PART + (size_t)4 * 128 * 2560;    // res h-side partials
                                                                   // (adjacent to 4 x-side chunks -> KS=8 read)

    // output offsets (floats)
    const size_t O_COND   = 0;
    const size_t O_STOP   = 81920;
    const size_t O_SCORES = 82048;
    const size_t O_ATTNH  = 213120;
    const size_t O_H1     = 245888;
    const size_t O_C1     = 311424;
    const size_t O_H2     = 376960;
    const size_t O_C2     = 442496;
    const size_t O_HS     = 508032;
    const size_t O_CS     = 835712;
    const size_t O_CTX    = 1163392;
    const size_t O_CUM    = 1196160;

    // PreNet fc1: N=256, K=128, KS=4 (KC=32)
    gemm_one_kernel<<<8 * 4, 256, 0, stream>>>(
        prenet_in, 128, fc1_w, 128, nullptr, 0, nullptr, 0,
        ws + OFF_PART, 256, 4, 32);
    reduce_act_kernel<<<128, 256, 0, stream>>>(ws + OFF_PART, 4, 128 * 256, fc1_b,
                                               ws + OFF_P, 256, 1);
    // PreNet fc2: N=128, K=256, KS=8 (KC=32)
    gemm_one_kernel<<<4 * 8, 256, 0, stream>>>(
        ws + OFF_P, 256, fc2_w, 256, nullptr, 0, nullptr, 0,
        ws + OFF_PART, 128, 8, 32);
    reduce_act_kernel<<<64, 256, 0, stream>>>(ws + OFF_PART, 8, 128 * 128, fc2_b,
                                              ws + OFF_POUT, 128, 1);

    // GRU gi (288 blocks, KS=12) + gh (192 blocks, KS=8) in one launch
    gemm_gru_kernel<<<480, 256, 0, stream>>>(
        context_vec, ws + OFF_POUT, attn_hidden, gru_wih, gru_whh,
        ws + OFF_PART, ws + OFF_PARTB);
    gru_gate_kernel<<<128, 256, 0, stream>>>(ws + OFF_PART, 12, ws + OFF_PARTB, 8,
                                             gru_bih, gru_bhh, attn_hidden, out + O_ATTNH);

    // pq: N=256, K=256, KS=8 (KC=32)
    gemm_one_kernel<<<8 * 8, 256, 0, stream>>>(
        out + O_ATTNH, 256, W_w, 256, nullptr, 0, nullptr, 0,
        ws + OFF_PART, 256, 8, 32);
    reduce_act_kernel<<<128, 256, 0, stream>>>(ws + OFF_PART, 8, 128 * 256, W_b,
                                               ws + OFF_PQ, 256, 0);

    attn_u_kernel<<<2048, 256, 0, stream>>>(encoder_seq_proj, ws + OFF_PQ, L_w,
                                            L_b, v_w, conv_w, cumulative, attn_prev,
                                            ws + OFF_SIG);
    attn_norm_kernel<<<128, 256, 0, stream>>>(ws + OFF_SIG, cumulative,
                                              out + O_SCORES, out + O_CUM, out + O_CTX);
    attn_ctx_kernel<<<1024, 256, 0, stream>>>(out + O_SCORES, encoder_seq, out + O_CTX);

    // x = [context | attn_h] @ ri_w^T + ri_b : N=512, K=256+256, KS=8 (KC=64)
    gemm_one_kernel<<<16 * 8, 256, 0, stream>>>(
        out + O_CTX, 256, ri_w, 512,
        out + O_ATTNH, 256, ri_w + 256, 512,
        ws + OFF_PART, 512, 8, 64);
    reduce_act_kernel<<<256, 256, 0, stream>>>(ws + OFF_PART, 8, 128 * 512, ri_b,
                                               ws + OFF_X, 512, 0);

    // LSTM 1: N=2048, K=512+512 (x-side | h-side as 2 segments), KS=4 (KC=256)
    gemm_one_kernel<<<64 * 4, 256, 0, stream>>>(
        ws + OFF_X, 512, r1_wih, 512,
        rnn1_h, 512, r1_whh, 512,
        ws + OFF_PART, 2048, 4, 256);
    lstm_gate_kernel<<<dim3(2, 128), 256, 0, stream>>>(
        ws + OFF_PART, 4, r1_bih, r1_bhh, rnn1_c, out + O_H1, out + O_C1,
        nullptr, 0, ws + OFF_X, 512, 0, ws + OFF_XB, 512);
    // LSTM 2: XC = XB + h2
    gemm_one_kernel<<<64 * 4, 256, 0, stream>>>(
        ws + OFF_XB, 512, r2_wih, 512,
        rnn2_h, 512, r2_whh, 512,
        ws + OFF_PART, 2048, 4, 256);
    lstm_gate_kernel<<<dim3(2, 128), 256, 0, stream>>>(
        ws + OFF_PART, 4, r2_bih, r2_bhh, rnn2_c, out + O_H2, out + O_C2,
        nullptr, 0, ws + OFF_XB, 512, 0, ws + OFF_XC, 512);

    // Residual stack: N=2560.  x-side K=640 -> 4 chunks at OFF_PART (KC=160);
    // h-side K=640 -> 4 chunks at OFF_PARTH (adjacent); gate reads KS=8.
    // Layer 0's x-side consumes [prenet(128) | XC(512)] via 2 segments.
    // Layer i>0 x input is the previous layer's x_new (ping-pong R0/R1);
    // layer 3 writes x_new (cond) straight to the output buffer.
    for (int i = 0; i < 4; ++i) {
        const float* wih = res_wih + (size_t)i * 2560 * 640;
        const float* whh = res_whh + (size_t)i * 2560 * 640;
        const float* hA  = res_h + (size_t)i * 81920;
        const float* cA  = res_c + (size_t)i * 81920;
        if (i == 0) {
            gemm_one_kernel<<<80 * 4, 256, 0, stream>>>(
                prenet_in, 128, wih, 640,
                ws + OFF_XC, 512, wih + 128, 640,
                ws + OFF_PART, 2560, 4, 160);
        } else {
            const float* rcur = ws + ((i & 1) ? OFF_R0 : OFF_R1);
            gemm_one_kernel<<<80 * 4, 256, 0, stream>>>(
                rcur, 640, wih, 640, nullptr, 0, nullptr, 0,
                ws + OFF_PART, 2560, 4, 160);
        }
        gemm_one_kernel<<<80 * 4, 256, 0, stream>>>(
            hA, 640, whh, 640, nullptr, 0, nullptr, 0,
            ws + OFF_PARTH, 2560, 4, 160);

        const float *xa, *xb; int sa, sb, split;
        if (i == 0) { xa = prenet_in; sa = 128; xb = ws + OFF_XC; sb = 512; split = 128; }
        else { xa = nullptr; sa = 0; xb = ws + ((i & 1) ? OFF_R0 : OFF_R1); sb = 640; split = 0; }
        float* xnew = (i == 3) ? (out + O_COND) : (ws + ((i & 1) ? OFF_R1 : OFF_R0));
        lstm_gate_kernel<<<dim3(3, 128), 256, 0, stream>>>(
            ws + OFF_PART, 8,
            res_bih + (size_t)i * 2560, res_bhh + (size_t)i * 2560,
            cA, out + O_HS + (size_t)i * 81920, out + O_CS + (size_t)i * 81920,
            xa, sa, xb, sb, split, xnew, 640);
    }

    stop_kernel<<<128, 64, 0, stream>>>(out + O_COND, stop_w, stop_b, out + O_STOP);
}